// Round 1
// baseline (352.128 us; speedup 1.0000x reference)
//
#include <hip/hip_runtime.h>
#include <hip/hip_bf16.h>

constexpr int B = 256, S = 1024, T = 64;
constexpr float LOG2E = 1.4426950408889634f;
constexpr float LN2   = 0.6931471805599453f;

// One wave (64 lanes) per batch chain. Lane j owns output tag j.
__global__ __launch_bounds__(64, 1) void crf_fwd(
        const float* __restrict__ emis, const int* __restrict__ tags,
        const float* __restrict__ U,    const float* __restrict__ bs,
        const float* __restrict__ be,   float* __restrict__ nll) {
    const int b = blockIdx.x;
    const int j = threadIdx.x;           // 0..63
    const float* eb = emis + (size_t)b * (S * T);
    const int*   tb = tags + (size_t)b * S;

    // W column j in registers: Wc[i] = e^{U[i][j]} = 2^{U*log2e}
    float Wc[T];
#pragma unroll
    for (int i = 0; i < T; ++i)
        Wc[i] = __builtin_amdgcn_exp2f(U[i * T + j] * LOG2E);

    // ---- path energy: emission gathers + transition gathers ----
    float pe = 0.f;
#pragma unroll
    for (int sc = 0; sc < S / 64; ++sc) {
        int s  = sc * 64 + j;
        int tg = tb[s];
        float e = eb[s * T + tg];
        if (s == 0)     e += bs[tg];
        if (s == S - 1) e += be[tg];
        pe += e;
        if (s < S - 1)  pe += U[tg * T + tb[s + 1]];
    }
#pragma unroll
    for (int m = 1; m < 64; m <<= 1) pe += __shfl_xor(pe, m, 64);

    // ---- forward recursion, log2 domain: beta = alpha * log2(e) ----
    float beta = (eb[j] + bs[j]) * LOG2E;     // t = 0
    float M = beta;                            // upper bound of max_j beta
#pragma unroll
    for (int m = 1; m < 64; m <<= 1) M = fmaxf(M, __shfl_xor(M, m, 64));

    float xn = eb[T + j];                      // prefetch x[t=1]
#pragma unroll 4
    for (int t = 1; t < S; ++t) {
        float x2 = xn;
        if (t == S - 1) x2 += be[j];
        x2 *= LOG2E;
        int tn = (t + 1 < S) ? t + 1 : S - 1;  // prefetch next x
        xn = eb[tn * T + j];

        // q_i = 2^{beta_i - M}  (<= 1 guaranteed since M >= max beta)
        float q = __builtin_amdgcn_exp2f(beta - M);

        // s_j = sum_i q_i * W[i][j]; q_i broadcast via readlane
        float s0 = 0.f, s1 = 0.f, s2 = 0.f, s3 = 0.f;
#pragma unroll
        for (int i = 0; i < T; i += 4) {
            float q0 = __uint_as_float(__builtin_amdgcn_readlane(__float_as_uint(q), i));
            float q1 = __uint_as_float(__builtin_amdgcn_readlane(__float_as_uint(q), i + 1));
            float q2 = __uint_as_float(__builtin_amdgcn_readlane(__float_as_uint(q), i + 2));
            float q3 = __uint_as_float(__builtin_amdgcn_readlane(__float_as_uint(q), i + 3));
            s0 = fmaf(q0, Wc[i],     s0);
            s1 = fmaf(q1, Wc[i + 1], s1);
            s2 = fmaf(q2, Wc[i + 2], s2);
            s3 = fmaf(q3, Wc[i + 3], s3);
        }
        float ss = (s0 + s1) + (s2 + s3);
        beta = M + __builtin_amdgcn_logf(ss) + x2;   // logf builtin == log2 HW op

        if ((t & 3) == 0) {
            // exact renorm every 4 steps (keeps M - maxbeta <= ~55)
            float m2 = beta;
#pragma unroll
            for (int m = 1; m < 64; m <<= 1) m2 = fmaxf(m2, __shfl_xor(m2, m, 64));
            M = m2;
        } else {
            // safe upper-bound growth: log2(64*Wmax)=6.33 plus 7-sigma x term
            M += 16.5f;
        }
    }

    // free energy = ln2 * log2-sum-exp2(beta)
    float Mf = beta;
#pragma unroll
    for (int m = 1; m < 64; m <<= 1) Mf = fmaxf(Mf, __shfl_xor(Mf, m, 64));
    float qf = __builtin_amdgcn_exp2f(beta - Mf);
#pragma unroll
    for (int m = 1; m < 64; m <<= 1) qf += __shfl_xor(qf, m, 64);
    float free_e = (Mf + __builtin_amdgcn_logf(qf)) * LN2;

    if (j == 0) nll[b] = free_e - pe;
}

__global__ __launch_bounds__(256, 1) void crf_reduce(const float* __restrict__ nll,
                                                     float* __restrict__ out) {
    float v = nll[threadIdx.x];
#pragma unroll
    for (int m = 1; m < 64; m <<= 1) v += __shfl_xor(v, m, 64);
    __shared__ float acc[4];
    if ((threadIdx.x & 63) == 0) acc[threadIdx.x >> 6] = v;
    __syncthreads();
    if (threadIdx.x == 0) out[0] = (acc[0] + acc[1] + acc[2] + acc[3]) * (1.0f / B);
}

extern "C" void kernel_launch(void* const* d_in, const int* in_sizes, int n_in,
                              void* d_out, int out_size, void* d_ws, size_t ws_size,
                              hipStream_t stream) {
    const float* emis = (const float*)d_in[0];
    const int*   tags = (const int*)d_in[1];
    const float* U    = (const float*)d_in[2];
    const float* bs   = (const float*)d_in[3];
    const float* be   = (const float*)d_in[4];
    float* nll = (float*)d_ws;   // 256 floats of scratch

    crf_fwd<<<dim3(B), dim3(64), 0, stream>>>(emis, tags, U, bs, be, nll);
    crf_reduce<<<dim3(1), dim3(256), 0, stream>>>(nll, (float*)d_out);
}

// Round 4
// 204.037 us; speedup vs baseline: 1.7258x; 1.7258x over previous
//
#include <hip/hip_runtime.h>
#include <hip/hip_bf16.h>

constexpr int B = 256, S = 1024, T = 64;
constexpr float LOG2E = 1.4426950408889634f;
constexpr float LN2   = 0.6931471805599453f;

typedef _Float16 h2 __attribute__((ext_vector_type(2)));

// pack two f32 into one f16x2 register word (RTZ)
static __device__ __forceinline__ unsigned int pack2(float lo, float hi) {
    return __builtin_bit_cast(unsigned int, __builtin_amdgcn_cvt_pkrtz(lo, hi));
}

// d = dot(a_half2, b_half2) + c via the fdot2 intrinsic (f32 accumulate)
static __device__ __forceinline__ float dot2f(unsigned int abits, h2 b, float c) {
    return __builtin_amdgcn_fdot2(__builtin_bit_cast(h2, abits), b, c, false);
}

// One wave per chain. Lane j owns tag j. State p_j ~ exp(alpha_j - ln2*C).
__global__ __launch_bounds__(64, 1) void crf_fwd(
        const float* __restrict__ emis, const int* __restrict__ tags,
        const float* __restrict__ U,    const float* __restrict__ bs,
        const float* __restrict__ be,   float* __restrict__ nll) {
    const int b = blockIdx.x;
    const int j = threadIdx.x;
    const float* eb = emis + (size_t)b * (S * T);
    const int*   tb = tags + (size_t)b * S;
    const float  bej = be[j];

    // W columns as packed f16 pairs: Wch[i] = (e^{U[2i][j]}, e^{U[2i+1][j]})
    h2 Wch[32];
#pragma unroll
    for (int i = 0; i < 32; ++i) {
        float w0 = __builtin_amdgcn_exp2f(U[(2 * i) * T + j] * LOG2E);
        float w1 = __builtin_amdgcn_exp2f(U[(2 * i + 1) * T + j] * LOG2E);
        Wch[i] = __builtin_bit_cast(h2, pack2(w0, w1));
    }

    // ---- path energy (exact, f32) ----
    float pe = 0.f;
#pragma unroll
    for (int sc = 0; sc < S / 64; ++sc) {
        int s  = sc * 64 + j;
        int tg = tb[s];
        float e = eb[s * T + tg];
        if (s == 0)     e += bs[tg];
        if (s == S - 1) e += be[tg];
        pe += e;
        if (s < S - 1)  pe += U[tg * T + tb[s + 1]];
    }
#pragma unroll
    for (int m = 1; m < 64; m <<= 1) pe += __shfl_xor(pe, m, 64);

    // ---- init: p = 2^{a0 - M0}, running log2-offset C = c2i + c2f ----
    float a0 = (eb[j] + bs[j]) * LOG2E;
    float M0 = a0;
#pragma unroll
    for (int m = 1; m < 64; m <<= 1) M0 = fmaxf(M0, __shfl_xor(M0, m, 64));
    float p   = __builtin_amdgcn_exp2f(a0 - M0);
    int   c2i = 0;
    const float c2f = M0;

    // one recursion step: p <- (W^T p) * e^{xval}, power-of-2 renorm
    auto step = [&](float xval) {
        float ex = __builtin_amdgcn_exp2f(xval * LOG2E);      // off critical chain
        float ph = __shfl_xor(p, 1, 64);
        unsigned int qb = pack2(p, ph);                        // even lane 2i: (p_2i, p_2i+1)
        float s0 = 0.f, s1 = 0.f, s2 = 0.f, s3 = 0.f;
#pragma unroll
        for (int i = 0; i < 32; i += 4) {
            s0 = dot2f(__builtin_amdgcn_readlane(qb, 2 * (i + 0)), Wch[i + 0], s0);
            s1 = dot2f(__builtin_amdgcn_readlane(qb, 2 * (i + 1)), Wch[i + 1], s1);
            s2 = dot2f(__builtin_amdgcn_readlane(qb, 2 * (i + 2)), Wch[i + 2], s2);
            s3 = dot2f(__builtin_amdgcn_readlane(qb, 2 * (i + 3)), Wch[i + 3], s3);
        }
        float ss = (s0 + s1) + (s2 + s3);
        // power-of-2 renorm anchored on lane 0 (cross-lane spread of ss <= 1.56x)
        unsigned int sb = __builtin_amdgcn_readfirstlane(__float_as_uint(ss));
        int ebits = (int)((sb >> 23) & 0xFF);
        float scale = __uint_as_float((unsigned int)(254 - ebits) << 23);
        c2i += ebits - 127;
        p = ss * scale * ex;
    };

    // ---- recursion t = 1..1023 with 8-deep ping-pong prefetch ----
    float xa[8], xb[8];
#pragma unroll
    for (int u = 0; u < 8; ++u) xa[u] = eb[(1 + u) * T + j];

    int t0 = 1;
    for (int k = 0; k < 63; ++k) {                 // 63 x 16 steps: t = 1..1008
#pragma unroll
        for (int u = 0; u < 8; ++u) xb[u] = eb[(t0 + 8 + u) * T + j];
#pragma unroll
        for (int u = 0; u < 8; ++u) step(xa[u]);   // t0 .. t0+7
#pragma unroll
        for (int u = 0; u < 8; ++u) xa[u] = eb[(t0 + 16 + u) * T + j];
#pragma unroll
        for (int u = 0; u < 8; ++u) step(xb[u]);   // t0+8 .. t0+15
        t0 += 16;
    }
    // t0 = 1009; xa holds x for t = 1009..1016
#pragma unroll
    for (int u = 0; u < 8; ++u) {
        int tt = t0 + 8 + u; if (tt > S - 1) tt = S - 1;  // t = 1017..1023 (clamped)
        xb[u] = eb[tt * T + j];
    }
#pragma unroll
    for (int u = 0; u < 8; ++u) step(xa[u]);       // t = 1009..1016
#pragma unroll
    for (int u = 0; u < 6; ++u) step(xb[u]);       // t = 1017..1022
    step(xb[6] + bej);                              // t = 1023 (+ b_end)

    // ---- free energy ----
    float sp = p;
#pragma unroll
    for (int m = 1; m < 64; m <<= 1) sp += __shfl_xor(sp, m, 64);
    float free_e = LN2 * (__builtin_amdgcn_logf(sp) + (float)c2i + c2f);

    if (j == 0) nll[b] = free_e - pe;
}

__global__ __launch_bounds__(256, 1) void crf_reduce(const float* __restrict__ nll,
                                                     float* __restrict__ out) {
    float v = nll[threadIdx.x];
#pragma unroll
    for (int m = 1; m < 64; m <<= 1) v += __shfl_xor(v, m, 64);
    __shared__ float acc[4];
    if ((threadIdx.x & 63) == 0) acc[threadIdx.x >> 6] = v;
    __syncthreads();
    if (threadIdx.x == 0) out[0] = (acc[0] + acc[1] + acc[2] + acc[3]) * (1.0f / B);
}

extern "C" void kernel_launch(void* const* d_in, const int* in_sizes, int n_in,
                              void* d_out, int out_size, void* d_ws, size_t ws_size,
                              hipStream_t stream) {
    const float* emis = (const float*)d_in[0];
    const int*   tags = (const int*)d_in[1];
    const float* U    = (const float*)d_in[2];
    const float* bs   = (const float*)d_in[3];
    const float* be   = (const float*)d_in[4];
    float* nll = (float*)d_ws;

    crf_fwd<<<dim3(B), dim3(64), 0, stream>>>(emis, tags, U, bs, be, nll);
    crf_reduce<<<dim3(1), dim3(256), 0, stream>>>(nll, (float*)d_out);
}